// Round 1
// baseline (1149.161 us; speedup 1.0000x reference)
//
#include <hip/hip_runtime.h>
#include <math.h>

#define EMB 128
#define MID 192
#define SEQ 128
#define BATCH 16
#define NPAIR 127
#define KCLS 5
#define EPSF 1e-5f

// ws float-offsets
#define OFF_WY    0                      // 256*128
#define OFF_BY    32768                  // 128
#define OFF_WXX   32896                  // 128*256
#define OFF_BXX   65664                  // 256
#define OFF_NODES 65920                  // B*128*128
#define OFF_YC    (65920+262144)         // B*127*128
#define OFF_L0    (65920+262144+260096)  // B*127

// ---------------- composite weights ----------------
__global__ void k_comp(const float* __restrict__ W1, const float* __restrict__ b1,
                       const float* __restrict__ W2, const float* __restrict__ b2,
                       const float* __restrict__ W3, const float* __restrict__ b3,
                       const float* __restrict__ W4, const float* __restrict__ b4,
                       float* __restrict__ ws) {
    int tid = blockIdx.x * blockDim.x + threadIdx.x;
    if (tid < 32768) {                    // Wy[k][o], k<256, o<128
        int k = tid >> 7, o = tid & 127;
        float a = 0.f;
        for (int j = 0; j < MID; ++j) a += W1[k*MID+j] * W2[j*EMB+o];
        ws[OFF_WY + tid] = a;
    } else if (tid < 65536) {             // Wxx[k][o], k<128, o<256
        int t = tid - 32768;
        int k = t >> 8, o = t & 255;
        float a = 0.f;
        for (int j = 0; j < MID; ++j) a += W3[k*MID+j] * W4[j*256+o];
        ws[OFF_WXX + t] = a;
    } else if (tid < 65536 + 128) {       // by
        int o = tid - 65536;
        float a = b2[o];
        for (int j = 0; j < MID; ++j) a += b1[j] * W2[j*EMB+o];
        ws[OFF_BY + o] = a;
    } else if (tid < 65536 + 128 + 256) { // bxx
        int o = tid - 65536 - 128;
        float a = b4[o];
        for (int j = 0; j < MID; ++j) a += b3[j] * W4[j*256+o];
        ws[OFF_BXX + o] = a;
    }
}

// ---------------- gather embeddings ----------------
__global__ void k_nodes(const int* __restrict__ inp, const float* __restrict__ emb,
                        float* __restrict__ ws) {
    int tid = blockIdx.x * blockDim.x + threadIdx.x;  // B*128*128
    if (tid >= BATCH*SEQ*EMB) return;
    int d = tid & 127;
    int bs = tid >> 7;       // b*128+k
    int tok = inp[bs];
    ws[OFF_NODES + tid] = emb[tok*EMB + d];
}

// ---------------- initial 127 pair losses (parallel, t=0 state) -------------
__global__ void __launch_bounds__(128) k_init(float* ws) {
    __shared__ float sx[2*EMB];   // [right(128), left(128)]
    __shared__ float sy[EMB];
    __shared__ float sxx[2*EMB];
    __shared__ float sls[2];
    int j = blockIdx.x % NPAIR, b = blockIdx.x / NPAIR;
    int tid = threadIdx.x;
    const float* nodes = ws + OFF_NODES + (size_t)b*SEQ*EMB;
    sx[tid]     = nodes[(j+1)*EMB + tid];   // right
    sx[tid+EMB] = nodes[j*EMB + tid];       // left
    __syncthreads();
    const float* Wy = ws + OFF_WY;
    float acc = ws[OFF_BY + tid];
    #pragma unroll 16
    for (int k = 0; k < 2*EMB; ++k) acc += sx[k] * Wy[k*EMB + tid];
    sy[tid] = acc;
    ws[OFF_YC + ((size_t)b*NPAIR + j)*EMB + tid] = acc;
    __syncthreads();
    const float* Wxx = ws + OFF_WXX;
    float a1 = ws[OFF_BXX + tid], a2 = ws[OFF_BXX + tid + EMB];
    #pragma unroll 8
    for (int k = 0; k < EMB; ++k) {
        float yv = sy[k];
        a1 += yv * Wxx[k*256 + tid];
        a2 += yv * Wxx[k*256 + tid + EMB];
    }
    sxx[tid] = a1; sxx[tid+EMB] = a2;
    __syncthreads();
    {   // softmax halves: wave h
        int h = tid >> 6, lane = tid & 63;
        float v0 = sxx[h*EMB + lane], v1 = sxx[h*EMB + lane + 64];
        float m = fmaxf(v0, v1);
        for (int s=32; s; s>>=1) m = fmaxf(m, __shfl_xor(m, s, 64));
        float se = expf(v0-m) + expf(v1-m);
        for (int s=32; s; s>>=1) se += __shfl_xor(se, s, 64);
        float lse = m + logf(se);
        float o0 = sx[h*EMB + lane], o1 = sx[h*EMB + lane + 64];
        float term = o0*(v0-lse) + o1*(v1-lse);
        for (int s=32; s; s>>=1) term += __shfl_xor(term, s, 64);
        if (lane == 0) sls[h] = -term;
    }
    __syncthreads();
    if (tid == 0) {
        float l = ((1.f+EPSF)*sls[0] + (1.f+EPSF)*sls[1]) / (2.f + EPSF);
        ws[OFF_L0 + b*NPAIR + j] = l;
    }
}

// ---------------- sequential scan: one block per batch row ------------------
__global__ void __launch_bounds__(256) k_seq(float* ws,
                      const float* __restrict__ Wk, const float* __restrict__ bkv,
                      float* out) {
    __shared__ float s_loss[NPAIR];
    __shared__ float s_cnt[SEQ];
    __shared__ int   s_nslot[SEQ];
    __shared__ int   s_yslot[NPAIR];
    __shared__ float s_x[2][2*EMB];
    __shared__ float s_y[2][EMB];
    __shared__ float s_xx[2][2*EMB];
    __shared__ float s_ls[2][2];
    __shared__ int   s_q[2];
    __shared__ float s_wv[4];
    __shared__ int   s_wi[4];
    __shared__ int   s_idx;
    __shared__ float s_min;
    __shared__ float s_log[KCLS];

    int b = blockIdx.x;
    int tid = threadIdx.x;
    float* nodes = ws + OFF_NODES + (size_t)b*SEQ*EMB;
    float* yc    = ws + OFF_YC    + (size_t)b*NPAIR*EMB;
    const float* Wy  = ws + OFF_WY;
    const float* by  = ws + OFF_BY;
    const float* Wxx = ws + OFF_WXX;
    const float* bxx = ws + OFF_BXX;

    if (tid < NPAIR) { s_loss[tid] = ws[OFF_L0 + b*NPAIR + tid]; s_yslot[tid] = tid; }
    if (tid < SEQ)   { s_cnt[tid] = 1.f; s_nslot[tid] = tid; }
    float acc = 0.f;
    __syncthreads();

    for (int t = 0; t < 127; ++t) {
        int L = SEQ - t;
        if (t > 0) {
            // recompute pairs s_q[0], s_q[1] (may be identical -> benign dup)
            int p = tid >> 7, kk = tid & 127;
            int q = s_q[p];
            s_x[p][kk]     = nodes[(size_t)s_nslot[q+1]*EMB + kk];  // right
            s_x[p][kk+EMB] = nodes[(size_t)s_nslot[q]*EMB + kk];    // left
            __syncthreads();
            float a = by[kk];
            #pragma unroll 16
            for (int k = 0; k < 2*EMB; ++k) a += s_x[p][k] * Wy[k*EMB + kk];
            s_y[p][kk] = a;
            yc[(size_t)s_yslot[q]*EMB + kk] = a;
            __syncthreads();
            float a1 = bxx[kk], a2 = bxx[kk+EMB];
            #pragma unroll 8
            for (int k = 0; k < EMB; ++k) {
                float yv = s_y[p][k];
                a1 += yv * Wxx[k*256 + kk];
                a2 += yv * Wxx[k*256 + kk + EMB];
            }
            s_xx[p][kk] = a1; s_xx[p][kk+EMB] = a2;
            __syncthreads();
            {   // per-wave softmax+loss-dot: wave w -> (pair p2, half h)
                int w = tid >> 6, lane = tid & 63;
                int p2 = w >> 1, h = w & 1;
                float v0 = s_xx[p2][h*EMB+lane], v1 = s_xx[p2][h*EMB+lane+64];
                float m = fmaxf(v0, v1);
                for (int s=32; s; s>>=1) m = fmaxf(m, __shfl_xor(m, s, 64));
                float se = expf(v0-m) + expf(v1-m);
                for (int s=32; s; s>>=1) se += __shfl_xor(se, s, 64);
                float lse = m + logf(se);
                float o0 = s_x[p2][h*EMB+lane], o1 = s_x[p2][h*EMB+lane+64];
                float term = o0*(v0-lse) + o1*(v1-lse);
                for (int s=32; s; s>>=1) term += __shfl_xor(term, s, 64);
                if (lane == 0) s_ls[p2][h] = -term;
            }
            __syncthreads();
            if (tid < 2) {
                int qq = s_q[tid];
                float n1 = s_cnt[qq+1], n2 = s_cnt[qq];
                s_loss[qq] = ((n1+EPSF)*s_ls[tid][0] + (n2+EPSF)*s_ls[tid][1]) / (n1+n2+EPSF);
            }
            __syncthreads();
        }
        // argmin over j in [0, L-2], first-occurrence tie rule
        {
            float v = (tid < L-1) ? s_loss[tid] : INFINITY;
            int ii = tid;
            for (int s=32; s; s>>=1) {
                float ov = __shfl_xor(v, s, 64);
                int   oi = __shfl_xor(ii, s, 64);
                if (ov < v || (ov == v && oi < ii)) { v = ov; ii = oi; }
            }
            int w = tid >> 6, lane = tid & 63;
            if (lane == 0) { s_wv[w] = v; s_wi[w] = ii; }
        }
        __syncthreads();
        if (tid == 0) {
            float bv = s_wv[0]; int bi = s_wi[0];
            for (int w = 1; w < 4; ++w) if (s_wv[w] < bv) { bv = s_wv[w]; bi = s_wi[w]; }
            s_idx = bi; s_min = bv;
        }
        __syncthreads();
        int idx = s_idx;
        if (tid == 0) acc += s_min;
        int pos = idx > 0 ? idx - 1 : 0;
        int slotF = s_nslot[pos];
        int ysI   = s_yslot[idx];
        float fcnt = s_cnt[idx] + s_cnt[idx == 0 ? L-1 : idx-1];
        // father node <- y of selected pair
        if (tid < EMB) nodes[(size_t)slotF*EMB + tid] = yc[(size_t)ysI*EMB + tid];
        // shifts (only when idx>0; reference does no shift for idx==0)
        bool doShift = (idx > 0);
        bool shL = doShift && tid >= pos+1 && tid <= L-3;   // loss / yslot
        bool shC = doShift && tid >= pos+1 && tid <= L-2;   // cnt / nslot
        float nl = 0.f, nc = 0.f; int nn = 0, ny = 0;
        if (shL) { nl = s_loss[tid+1]; ny = s_yslot[tid+1]; }
        if (shC) { nc = s_cnt[tid+1];  nn = s_nslot[tid+1]; }
        __syncthreads();
        if (shL) { s_loss[tid] = nl; s_yslot[tid] = ny; }
        if (shC) { s_cnt[tid]  = nc; s_nslot[tid] = nn; }
        if (tid == 0) {
            s_cnt[pos] = fcnt;
            s_q[0] = (pos >= 1) ? pos - 1 : pos;
            s_q[1] = pos;
        }
        __syncthreads();
    }
    // prediction from final root node
    if (tid < KCLS) {
        int slot0 = s_nslot[0];
        float a = bkv[tid];
        for (int k = 0; k < EMB; ++k) a += nodes[(size_t)slot0*EMB + k] * Wk[k*KCLS + tid];
        s_log[tid] = a;
    }
    __syncthreads();
    if (tid == 0) {
        int best = 0;
        for (int c = 1; c < KCLS; ++c) if (s_log[c] > s_log[best]) best = c;
        out[b] = (float)best;
        atomicAdd(&out[BATCH], acc * (1.f/16.f));
    }
}

extern "C" void kernel_launch(void* const* d_in, const int* in_sizes, int n_in,
                              void* d_out, int out_size, void* d_ws, size_t ws_size,
                              hipStream_t stream) {
    const int*   inp = (const int*)d_in[0];
    const float* emb = (const float*)d_in[1];
    const float* W1  = (const float*)d_in[2];
    const float* b1  = (const float*)d_in[3];
    const float* W2  = (const float*)d_in[4];
    const float* b2  = (const float*)d_in[5];
    const float* W3  = (const float*)d_in[6];
    const float* b3  = (const float*)d_in[7];
    const float* W4  = (const float*)d_in[8];
    const float* b4  = (const float*)d_in[9];
    const float* Wk  = (const float*)d_in[10];
    const float* bk  = (const float*)d_in[11];
    float* out = (float*)d_out;
    float* ws  = (float*)d_ws;

    hipMemsetAsync(d_out, 0, (size_t)out_size * sizeof(float), stream);

    k_comp<<<(65920 + 255) / 256, 256, 0, stream>>>(W1, b1, W2, b2, W3, b3, W4, b4, ws);
    k_nodes<<<(BATCH*SEQ*EMB + 255) / 256, 256, 0, stream>>>(inp, emb, ws);
    k_init<<<BATCH * NPAIR, 128, 0, stream>>>(ws);
    k_seq<<<BATCH, 256, 0, stream>>>(ws, Wk, bk, out);
}

// Round 2
// 777.489 us; speedup vs baseline: 1.4780x; 1.4780x over previous
//
#include <hip/hip_runtime.h>
#include <math.h>

#define EMB 128
#define MID 192
#define SEQ 128
#define BATCH 16
#define NPAIR 127
#define KCLS 5
#define EPSF 1e-5f

// ws float-offsets
#define OFF_WY    0                      // 256*128
#define OFF_BY    32768                  // 128
#define OFF_WXX   32896                  // 128*256
#define OFF_BXX   65664                  // 256
#define OFF_NODES 65920                  // B*128*128
#define OFF_YC    (65920+262144)         // B*127*128
#define OFF_L0    (65920+262144+260096)  // B*127

// ---------------- composite weights ----------------
__global__ void k_comp(const float* __restrict__ W1, const float* __restrict__ b1,
                       const float* __restrict__ W2, const float* __restrict__ b2,
                       const float* __restrict__ W3, const float* __restrict__ b3,
                       const float* __restrict__ W4, const float* __restrict__ b4,
                       float* __restrict__ ws) {
    int tid = blockIdx.x * blockDim.x + threadIdx.x;
    if (tid < 32768) {                    // Wy[k][o], k<256, o<128
        int k = tid >> 7, o = tid & 127;
        float a = 0.f;
        for (int j = 0; j < MID; ++j) a += W1[k*MID+j] * W2[j*EMB+o];
        ws[OFF_WY + tid] = a;
    } else if (tid < 65536) {             // Wxx[k][o], k<128, o<256
        int t = tid - 32768;
        int k = t >> 8, o = t & 255;
        float a = 0.f;
        for (int j = 0; j < MID; ++j) a += W3[k*MID+j] * W4[j*256+o];
        ws[OFF_WXX + t] = a;
    } else if (tid < 65536 + 128) {       // by
        int o = tid - 65536;
        float a = b2[o];
        for (int j = 0; j < MID; ++j) a += b1[j] * W2[j*EMB+o];
        ws[OFF_BY + o] = a;
    } else if (tid < 65536 + 128 + 256) { // bxx
        int o = tid - 65536 - 128;
        float a = b4[o];
        for (int j = 0; j < MID; ++j) a += b3[j] * W4[j*256+o];
        ws[OFF_BXX + o] = a;
    }
}

// ---------------- gather embeddings ----------------
__global__ void k_nodes(const int* __restrict__ inp, const float* __restrict__ emb,
                        float* __restrict__ ws) {
    int tid = blockIdx.x * blockDim.x + threadIdx.x;  // B*128*128
    if (tid >= BATCH*SEQ*EMB) return;
    int d = tid & 127;
    int bs = tid >> 7;       // b*128+k
    int tok = inp[bs];
    ws[OFF_NODES + tid] = emb[tok*EMB + d];
}

// ---------------- initial 127 pair losses: 8 groups x 16 rows --------------
// Register-held composite weights; each block computes 16 pairs (2 at a time).
__global__ void __launch_bounds__(256, 1) k_init(float* __restrict__ ws) {
    __shared__ float s_x[2][2*EMB];
    __shared__ float s_red[4][EMB];
    __shared__ float s_y[2][EMB];
    __shared__ float s_xx[2][2*EMB];
    __shared__ float s_by[EMB];
    __shared__ float s_bxx[2*EMB];
    __shared__ float s_ls[2][2];
    int tid = threadIdx.x;
    int b = blockIdx.x >> 3, g = blockIdx.x & 7;
    int h = tid >> 7, o = tid & 127;
    float wy[128], wxx[128];
    #pragma unroll
    for (int k = 0; k < 128; ++k) wy[k] = ws[OFF_WY + (h*128 + k)*EMB + o];
    #pragma unroll
    for (int k = 0; k < 128; ++k) wxx[k] = ws[OFF_WXX + k*256 + tid];
    if (tid < EMB) s_by[tid] = ws[OFF_BY + tid];
    s_bxx[tid] = ws[OFF_BXX + tid];
    const float* nodes = ws + OFF_NODES + (size_t)b*SEQ*EMB;
    float* yc = ws + OFF_YC + (size_t)b*NPAIR*EMB;
    __syncthreads();
    for (int i = 0; i < 8; ++i) {
        int j = g*16 + i*2 + h;
        int jj = j < NPAIR ? j : NPAIR - 1;
        s_x[h][o]     = nodes[(jj+1)*EMB + o];
        s_x[h][o+EMB] = nodes[jj*EMB + o];
        __syncthreads();
        float a0 = 0.f, a1 = 0.f;
        #pragma unroll
        for (int k = 0; k < 128; ++k) {
            float w = wy[k];
            a0 += s_x[0][h*128 + k] * w;
            a1 += s_x[1][h*128 + k] * w;
        }
        s_red[h*2+0][o] = a0;
        s_red[h*2+1][o] = a1;
        __syncthreads();
        if (tid < EMB) {
            #pragma unroll
            for (int p2 = 0; p2 < 2; ++p2) {
                float yv = s_red[p2][tid] + s_red[2+p2][tid] + s_by[tid];
                s_y[p2][tid] = yv;
                int j2 = g*16 + i*2 + p2;
                if (j2 < NPAIR) yc[(size_t)j2*EMB + tid] = yv;
            }
        }
        __syncthreads();
        float c0 = s_bxx[tid], c1 = s_bxx[tid];
        #pragma unroll
        for (int k = 0; k < 128; ++k) {
            float w = wxx[k];
            c0 += s_y[0][k] * w;
            c1 += s_y[1][k] * w;
        }
        s_xx[0][tid] = c0;
        s_xx[1][tid] = c1;
        __syncthreads();
        {
            int w = tid >> 6, lane = tid & 63;
            int p2 = w >> 1, h2 = w & 1;
            float v0 = s_xx[p2][h2*EMB + lane], v1 = s_xx[p2][h2*EMB + lane + 64];
            float m = fmaxf(v0, v1);
            for (int s = 32; s; s >>= 1) m = fmaxf(m, __shfl_xor(m, s, 64));
            float se = expf(v0 - m) + expf(v1 - m);
            for (int s = 32; s; s >>= 1) se += __shfl_xor(se, s, 64);
            float lse = m + logf(se);
            float o0 = s_x[p2][h2*EMB + lane], o1 = s_x[p2][h2*EMB + lane + 64];
            float term = o0*(v0 - lse) + o1*(v1 - lse);
            for (int s = 32; s; s >>= 1) term += __shfl_xor(term, s, 64);
            if (lane == 0) s_ls[p2][h2] = -term;
        }
        __syncthreads();
        if (tid < 2) {
            int j2 = g*16 + i*2 + tid;
            if (j2 < NPAIR) {
                float l = ((1.f+EPSF)*s_ls[tid][0] + (1.f+EPSF)*s_ls[tid][1]) / (2.f + EPSF);
                ws[OFF_L0 + b*NPAIR + j2] = l;
            }
        }
        __syncthreads();
    }
}

// ---------------- sequential scan: one block per batch row ------------------
// Weights in VGPRs (wy/wxx, 256 regs), nodes + y-cache in LDS (~138 KB total).
__global__ void __launch_bounds__(256, 1) k_seq(float* __restrict__ ws,
                      const float* __restrict__ Wk, const float* __restrict__ bkv,
                      float* __restrict__ out) {
    __shared__ float s_nodes[SEQ*EMB];    // 64 KB
    __shared__ float s_yc[NPAIR*EMB];     // 63.5 KB
    __shared__ float s_x[2][2*EMB];
    __shared__ float s_red[4][EMB];
    __shared__ float s_y[2][EMB];
    __shared__ float s_xx[2][2*EMB];
    __shared__ float s_by[EMB];
    __shared__ float s_bxx[2*EMB];
    __shared__ float s_ls[2][2];
    __shared__ float s_loss[NPAIR];
    __shared__ float s_cnt[SEQ];
    __shared__ int   s_nslot[SEQ];
    __shared__ int   s_yslot[NPAIR];
    __shared__ int   s_q[2];
    __shared__ float s_wv[2];
    __shared__ int   s_wi[2];
    __shared__ float s_log[KCLS];

    int tid = threadIdx.x;
    int b = blockIdx.x;
    int h = tid >> 7, o = tid & 127;
    float wy[128], wxx[128];
    #pragma unroll
    for (int k = 0; k < 128; ++k) wy[k] = ws[OFF_WY + (h*128 + k)*EMB + o];
    #pragma unroll
    for (int k = 0; k < 128; ++k) wxx[k] = ws[OFF_WXX + k*256 + tid];
    {
        const float* gn = ws + OFF_NODES + (size_t)b*SEQ*EMB;
        for (int i = tid; i < SEQ*EMB; i += 256) s_nodes[i] = gn[i];
        const float* gy = ws + OFF_YC + (size_t)b*NPAIR*EMB;
        for (int i = tid; i < NPAIR*EMB; i += 256) s_yc[i] = gy[i];
    }
    if (tid < EMB) s_by[tid] = ws[OFF_BY + tid];
    s_bxx[tid] = ws[OFF_BXX + tid];
    if (tid < NPAIR) { s_loss[tid] = ws[OFF_L0 + b*NPAIR + tid]; s_yslot[tid] = tid; }
    if (tid < SEQ)   { s_cnt[tid] = 1.f; s_nslot[tid] = tid; }
    float acc = 0.f;
    __syncthreads();

    #pragma unroll 1
    for (int t = 0; t < NPAIR; ++t) {
        int L = SEQ - t;
        if (t > 0) {
            // stage x for the two affected pairs s_q[0], s_q[1]
            {
                int q = s_q[h];
                s_x[h][o]     = s_nodes[s_nslot[q+1]*EMB + o];   // right
                s_x[h][o+EMB] = s_nodes[s_nslot[q]*EMB + o];     // left
            }
            __syncthreads();
            // y partials: thread (h,o) handles k-half h of output o, both pairs
            float a0 = 0.f, a1 = 0.f;
            #pragma unroll
            for (int k = 0; k < 128; ++k) {
                float w = wy[k];
                a0 += s_x[0][h*128 + k] * w;
                a1 += s_x[1][h*128 + k] * w;
            }
            s_red[h*2+0][o] = a0;
            s_red[h*2+1][o] = a1;
            __syncthreads();
            if (tid < EMB) {
                #pragma unroll
                for (int p2 = 0; p2 < 2; ++p2) {
                    float yv = s_red[p2][tid] + s_red[2+p2][tid] + s_by[tid];
                    s_y[p2][tid] = yv;
                    s_yc[(size_t)s_yslot[s_q[p2]]*EMB + tid] = yv;
                }
            }
            __syncthreads();
            // xx: thread owns output column tid (0..255), both pairs
            float c0 = s_bxx[tid], c1 = s_bxx[tid];
            #pragma unroll
            for (int k = 0; k < 128; ++k) {
                float w = wxx[k];
                c0 += s_y[0][k] * w;
                c1 += s_y[1][k] * w;
            }
            s_xx[0][tid] = c0;
            s_xx[1][tid] = c1;
            __syncthreads();
            {   // per-wave softmax+loss-dot: wave w -> (pair p2, half h2)
                int w = tid >> 6, lane = tid & 63;
                int p2 = w >> 1, h2 = w & 1;
                float v0 = s_xx[p2][h2*EMB + lane], v1 = s_xx[p2][h2*EMB + lane + 64];
                float m = fmaxf(v0, v1);
                for (int s = 32; s; s >>= 1) m = fmaxf(m, __shfl_xor(m, s, 64));
                float se = expf(v0 - m) + expf(v1 - m);
                for (int s = 32; s; s >>= 1) se += __shfl_xor(se, s, 64);
                float lse = m + logf(se);
                float o0 = s_x[p2][h2*EMB + lane], o1 = s_x[p2][h2*EMB + lane + 64];
                float term = o0*(v0 - lse) + o1*(v1 - lse);
                for (int s = 32; s; s >>= 1) term += __shfl_xor(term, s, 64);
                if (lane == 0) s_ls[p2][h2] = -term;
            }
            __syncthreads();
            if (tid < 2) {
                int qq = s_q[tid];
                float n1 = s_cnt[qq+1], n2 = s_cnt[qq];
                s_loss[qq] = ((n1+EPSF)*s_ls[tid][0] + (n2+EPSF)*s_ls[tid][1]) / (n1+n2+EPSF);
            }
            __syncthreads();
        }
        // argmin over j in [0, L-1), first-occurrence tie rule; waves 0,1 cover 0..127
        if (tid < 128) {
            float v = (tid < L-1) ? s_loss[tid] : INFINITY;
            int ii = tid;
            for (int s = 32; s; s >>= 1) {
                float ov = __shfl_xor(v, s, 64);
                int   oi = __shfl_xor(ii, s, 64);
                if (ov < v || (ov == v && oi < ii)) { v = ov; ii = oi; }
            }
            if ((tid & 63) == 0) { s_wv[tid>>6] = v; s_wi[tid>>6] = ii; }
        }
        __syncthreads();
        float bv0 = s_wv[0], bv1 = s_wv[1];
        int idx = (s_wv[1] < s_wv[0]) ? s_wi[1] : s_wi[0];
        if (tid == 0) acc += fminf(bv0, bv1);
        int pos = idx > 0 ? idx - 1 : 0;
        int slotF = s_nslot[pos];
        int ysI   = s_yslot[idx];
        float fcnt = s_cnt[idx] + s_cnt[idx == 0 ? L-1 : idx-1];
        // shifts (only when idx>0; reference does no shift for idx==0)
        bool doShift = (idx > 0);
        bool shL = doShift && tid >= pos+1 && tid <= L-3;   // loss / yslot
        bool shC = doShift && tid >= pos+1 && tid <= L-2;   // cnt / nslot
        float nl = 0.f, nc = 0.f; int nn = 0, ny = 0;
        if (shL) { nl = s_loss[tid+1]; ny = s_yslot[tid+1]; }
        if (shC) { nc = s_cnt[tid+1];  nn = s_nslot[tid+1]; }
        float fx = (tid < EMB) ? s_yc[(size_t)ysI*EMB + tid] : 0.f;
        __syncthreads();
        if (tid < EMB) s_nodes[slotF*EMB + tid] = fx;   // father node <- y of pair
        if (shL) { s_loss[tid] = nl; s_yslot[tid] = ny; }
        if (shC) { s_cnt[tid]  = nc; s_nslot[tid] = nn; }
        if (tid == 0) {
            s_cnt[pos] = fcnt;
            s_q[0] = (pos >= 1) ? pos - 1 : pos;
            s_q[1] = pos;
        }
        __syncthreads();
    }
    // prediction from final root node
    if (tid < KCLS) {
        int slot0 = s_nslot[0];
        float a = bkv[tid];
        for (int k = 0; k < EMB; ++k) a += s_nodes[slot0*EMB + k] * Wk[k*KCLS + tid];
        s_log[tid] = a;
    }
    __syncthreads();
    if (tid == 0) {
        int best = 0;
        for (int c = 1; c < KCLS; ++c) if (s_log[c] > s_log[best]) best = c;
        out[b] = (float)best;
        atomicAdd(&out[BATCH], acc * (1.f/16.f));
    }
}

extern "C" void kernel_launch(void* const* d_in, const int* in_sizes, int n_in,
                              void* d_out, int out_size, void* d_ws, size_t ws_size,
                              hipStream_t stream) {
    const int*   inp = (const int*)d_in[0];
    const float* emb = (const float*)d_in[1];
    const float* W1  = (const float*)d_in[2];
    const float* b1  = (const float*)d_in[3];
    const float* W2  = (const float*)d_in[4];
    const float* b2  = (const float*)d_in[5];
    const float* W3  = (const float*)d_in[6];
    const float* b3  = (const float*)d_in[7];
    const float* W4  = (const float*)d_in[8];
    const float* b4  = (const float*)d_in[9];
    const float* Wk  = (const float*)d_in[10];
    const float* bk  = (const float*)d_in[11];
    float* out = (float*)d_out;
    float* ws  = (float*)d_ws;

    hipMemsetAsync(d_out, 0, (size_t)out_size * sizeof(float), stream);

    k_comp<<<(65920 + 255) / 256, 256, 0, stream>>>(W1, b1, W2, b2, W3, b3, W4, b4, ws);
    k_nodes<<<(BATCH*SEQ*EMB + 255) / 256, 256, 0, stream>>>(inp, emb, ws);
    k_init<<<BATCH * 8, 256, 0, stream>>>(ws);
    k_seq<<<BATCH, 256, 0, stream>>>(ws, Wk, bk, out);
}

// Round 3
// 550.875 us; speedup vs baseline: 2.0861x; 1.4114x over previous
//
#include <hip/hip_runtime.h>
#include <math.h>

#define EMB 128
#define MID 192
#define SEQ 128
#define BATCH 16
#define NPAIR 127
#define KCLS 5
#define EPSF 1e-5f

// ws float-offsets
// WYT: thread-transposed Wy. Thread t = q*128+o (q=k-quarter, o=output) holds
//      WYT[t*64+j] = Wy[q*64+j][o].
// WXXT: thread t = hh*256+c (hh=k-half, c=col) holds WXXT[t*64+j] = Wxx[hh*64+j][c].
#define OFF_WYT   0                      // 512*64 = 32768
#define OFF_BY    32768                  // 128
#define OFF_WXXT  32896                  // 512*64 = 32768
#define OFF_BXX   65664                  // 256
#define OFF_NODES 65920                  // B*128*128 = 262144
#define OFF_YC    328064                 // B*127*128 = 260096
#define OFF_L0    588160                 // B*127

// ---------------- composite weights (transposed for per-thread slices) ------
__global__ void k_comp(const float* __restrict__ W1, const float* __restrict__ b1,
                       const float* __restrict__ W2, const float* __restrict__ b2,
                       const float* __restrict__ W3, const float* __restrict__ b3,
                       const float* __restrict__ W4, const float* __restrict__ b4,
                       float* __restrict__ ws) {
    int tid = blockIdx.x * blockDim.x + threadIdx.x;
    if (tid < 32768) {                    // Wy[k][o], k<256, o<128
        int k = tid >> 7, o = tid & 127;
        float a = 0.f;
        for (int j = 0; j < MID; ++j) a += W1[k*MID+j] * W2[j*EMB+o];
        int q = k >> 6, jj = k & 63;
        ws[OFF_WYT + (size_t)(q*128 + o)*64 + jj] = a;
    } else if (tid < 65536) {             // Wxx[k][c], k<128, c<256
        int t = tid - 32768;
        int k = t >> 8, c = t & 255;
        float a = 0.f;
        for (int j = 0; j < MID; ++j) a += W3[k*MID+j] * W4[j*256+c];
        int hh = k >> 6, jj = k & 63;
        ws[OFF_WXXT + (size_t)(hh*256 + c)*64 + jj] = a;
    } else if (tid < 65536 + 128) {       // by
        int o = tid - 65536;
        float a = b2[o];
        for (int j = 0; j < MID; ++j) a += b1[j] * W2[j*EMB+o];
        ws[OFF_BY + o] = a;
    } else if (tid < 65536 + 128 + 256) { // bxx
        int o = tid - 65536 - 128;
        float a = b4[o];
        for (int j = 0; j < MID; ++j) a += b3[j] * W4[j*256+o];
        ws[OFF_BXX + o] = a;
    }
}

// ---------------- gather embeddings ----------------
__global__ void k_nodes(const int* __restrict__ inp, const float* __restrict__ emb,
                        float* __restrict__ ws) {
    int tid = blockIdx.x * blockDim.x + threadIdx.x;  // B*128*128
    if (tid >= BATCH*SEQ*EMB) return;
    int d = tid & 127;
    int bs = tid >> 7;
    int tok = inp[bs];
    ws[OFF_NODES + tid] = emb[tok*EMB + d];
}

// ---------------- initial 127 pair losses: 8 groups x 16 rows ---------------
__global__ void __launch_bounds__(512, 2) k_init(float* __restrict__ ws) {
    __shared__ float s_x[2][2*EMB];
    __shared__ float s_red[4][2][EMB];
    __shared__ float s_redx[2][2][256];
    __shared__ float s_y[2][EMB];
    __shared__ float s_by[EMB];
    __shared__ float s_bxx[2*EMB];
    __shared__ float s_ls[2][2];
    int tid = threadIdx.x;
    int b = blockIdx.x >> 3, g = blockIdx.x & 7;
    float wy[64], wxx[64];
    {
        const float4* gw = (const float4*)(ws + OFF_WYT) + (size_t)tid*16;
        #pragma unroll
        for (int i = 0; i < 16; ++i) { float4 v = gw[i]; wy[4*i]=v.x; wy[4*i+1]=v.y; wy[4*i+2]=v.z; wy[4*i+3]=v.w; }
        const float4* gx = (const float4*)(ws + OFF_WXXT) + (size_t)tid*16;
        #pragma unroll
        for (int i = 0; i < 16; ++i) { float4 v = gx[i]; wxx[4*i]=v.x; wxx[4*i+1]=v.y; wxx[4*i+2]=v.z; wxx[4*i+3]=v.w; }
    }
    if (tid < EMB) s_by[tid] = ws[OFF_BY + tid];
    if (tid < 2*EMB) s_bxx[tid] = ws[OFF_BXX + tid];
    const float* nodes = ws + OFF_NODES + (size_t)b*SEQ*EMB;
    float* yc = ws + OFF_YC + (size_t)b*NPAIR*EMB;
    int q4 = tid >> 7, o = tid & 127;
    int hh = tid >> 8, c = tid & 255;
    int p_s = tid >> 8, kk = tid & 255;
    __syncthreads();
    for (int i = 0; i < 8; ++i) {
        int base = g*16 + i*2;
        {
            int j = base + p_s;
            int jj = j < NPAIR ? j : NPAIR - 1;
            s_x[p_s][kk] = nodes[(jj + (kk < 128 ? 1 : 0))*EMB + (kk & 127)];
        }
        __syncthreads();
        float a0 = 0.f, a1 = 0.f;
        #pragma unroll
        for (int j = 0; j < 64; ++j) {
            float w = wy[j];
            a0 += s_x[0][q4*64 + j] * w;
            a1 += s_x[1][q4*64 + j] * w;
        }
        s_red[q4][0][o] = a0;
        s_red[q4][1][o] = a1;
        __syncthreads();
        if (tid < 256) {
            int p = tid >> 7, oo = tid & 127;
            float yv = s_red[0][p][oo] + s_red[1][p][oo] + s_red[2][p][oo] + s_red[3][p][oo] + s_by[oo];
            s_y[p][oo] = yv;
            int j2 = base + p;
            if (j2 < NPAIR) yc[(size_t)j2*EMB + oo] = yv;
        }
        __syncthreads();
        float c0 = 0.f, c1 = 0.f;
        #pragma unroll
        for (int j = 0; j < 64; ++j) {
            float w = wxx[j];
            c0 += s_y[0][hh*64 + j] * w;
            c1 += s_y[1][hh*64 + j] * w;
        }
        s_redx[hh][0][c] = c0;
        s_redx[hh][1][c] = c1;
        __syncthreads();
        if (tid < 256) {   // waves 0-3: (pair p2, half h2)
            int w = tid >> 6, lane = tid & 63;
            int p2 = w >> 1, h2 = w & 1;
            int cA = h2*128 + lane, cB = cA + 64;
            float v0 = s_redx[0][p2][cA] + s_redx[1][p2][cA] + s_bxx[cA];
            float v1 = s_redx[0][p2][cB] + s_redx[1][p2][cB] + s_bxx[cB];
            float m = fmaxf(v0, v1);
            for (int s = 32; s; s >>= 1) m = fmaxf(m, __shfl_xor(m, s, 64));
            float se = expf(v0 - m) + expf(v1 - m);
            for (int s = 32; s; s >>= 1) se += __shfl_xor(se, s, 64);
            float lse = m + logf(se);
            float o0 = s_x[p2][cA], o1 = s_x[p2][cB];
            float term = o0*(v0 - lse) + o1*(v1 - lse);
            for (int s = 32; s; s >>= 1) term += __shfl_xor(term, s, 64);
            if (lane == 0) s_ls[p2][h2] = -term;
        }
        __syncthreads();
        if (tid < 2) {
            int j2 = base + tid;
            if (j2 < NPAIR) {
                float l = ((1.f+EPSF)*s_ls[tid][0] + (1.f+EPSF)*s_ls[tid][1]) / (2.f + EPSF);
                ws[OFF_L0 + b*NPAIR + j2] = l;
            }
        }
        __syncthreads();
    }
}

// ---------------- sequential scan: one block (512 thr) per batch row --------
__global__ void __launch_bounds__(512, 2) k_seq(float* __restrict__ ws,
                      const float* __restrict__ Wk, const float* __restrict__ bkv,
                      float* __restrict__ out) {
    __shared__ float s_nodes[SEQ*EMB];    // 64 KB
    __shared__ float s_yc[NPAIR*EMB];     // 63.5 KB
    __shared__ float s_x[2][2*EMB];
    __shared__ float s_red[4][2][EMB];
    __shared__ float s_redx[2][2][256];
    __shared__ float s_y[2][EMB];
    __shared__ float s_by[EMB];
    __shared__ float s_bxx[2*EMB];
    __shared__ float s_ls[2][2];
    __shared__ float s_loss[NPAIR];
    __shared__ float s_cnt[SEQ];
    __shared__ int   s_nslot[SEQ];
    __shared__ int   s_yslot[NPAIR];
    __shared__ int   s_q[2];
    __shared__ float s_wv[2];
    __shared__ int   s_wi[2];
    __shared__ float s_log[KCLS];

    int tid = threadIdx.x;
    int b = blockIdx.x;
    float wy[64], wxx[64];
    {
        const float4* gw = (const float4*)(ws + OFF_WYT) + (size_t)tid*16;
        #pragma unroll
        for (int i = 0; i < 16; ++i) { float4 v = gw[i]; wy[4*i]=v.x; wy[4*i+1]=v.y; wy[4*i+2]=v.z; wy[4*i+3]=v.w; }
        const float4* gx = (const float4*)(ws + OFF_WXXT) + (size_t)tid*16;
        #pragma unroll
        for (int i = 0; i < 16; ++i) { float4 v = gx[i]; wxx[4*i]=v.x; wxx[4*i+1]=v.y; wxx[4*i+2]=v.z; wxx[4*i+3]=v.w; }
    }
    {
        const float4* gn = (const float4*)(ws + OFF_NODES + (size_t)b*SEQ*EMB);
        float4* sn = (float4*)s_nodes;
        for (int i = tid; i < SEQ*EMB/4; i += 512) sn[i] = gn[i];
        const float4* gy = (const float4*)(ws + OFF_YC + (size_t)b*NPAIR*EMB);
        float4* sy = (float4*)s_yc;
        for (int i = tid; i < NPAIR*EMB/4; i += 512) sy[i] = gy[i];
    }
    if (tid < EMB) s_by[tid] = ws[OFF_BY + tid];
    if (tid < 2*EMB) s_bxx[tid] = ws[OFF_BXX + tid];
    if (tid < NPAIR) { s_loss[tid] = ws[OFF_L0 + b*NPAIR + tid]; s_yslot[tid] = tid; }
    if (tid < SEQ)   { s_cnt[tid] = 1.f; s_nslot[tid] = tid; }
    float acc = 0.f;
    int q4 = tid >> 7, o = tid & 127;
    int hh = tid >> 8, c = tid & 255;
    int p_s = tid >> 8, kk = tid & 255;
    __syncthreads();

    #pragma unroll 1
    for (int t = 0; t < NPAIR; ++t) {
        int L = SEQ - t;
        if (t > 0) {
            {   // stage x for the two affected pairs
                int q = s_q[p_s];
                s_x[p_s][kk] = s_nodes[s_nslot[q + (kk < 128 ? 1 : 0)]*EMB + (kk & 127)];
            }
            __syncthreads();
            float a0 = 0.f, a1 = 0.f;
            #pragma unroll
            for (int j = 0; j < 64; ++j) {
                float w = wy[j];
                a0 += s_x[0][q4*64 + j] * w;
                a1 += s_x[1][q4*64 + j] * w;
            }
            s_red[q4][0][o] = a0;
            s_red[q4][1][o] = a1;
            __syncthreads();
            if (tid < 256) {
                int p = tid >> 7, oo = tid & 127;
                float yv = s_red[0][p][oo] + s_red[1][p][oo] + s_red[2][p][oo] + s_red[3][p][oo] + s_by[oo];
                s_y[p][oo] = yv;
                s_yc[(size_t)s_yslot[s_q[p]]*EMB + oo] = yv;
            }
            __syncthreads();
            float c0 = 0.f, c1 = 0.f;
            #pragma unroll
            for (int j = 0; j < 64; ++j) {
                float w = wxx[j];
                c0 += s_y[0][hh*64 + j] * w;
                c1 += s_y[1][hh*64 + j] * w;
            }
            s_redx[hh][0][c] = c0;
            s_redx[hh][1][c] = c1;
            __syncthreads();
            if (tid < 256) {   // waves 0-3: (pair p2, half h2)
                int w = tid >> 6, lane = tid & 63;
                int p2 = w >> 1, h2 = w & 1;
                int cA = h2*128 + lane, cB = cA + 64;
                float v0 = s_redx[0][p2][cA] + s_redx[1][p2][cA] + s_bxx[cA];
                float v1 = s_redx[0][p2][cB] + s_redx[1][p2][cB] + s_bxx[cB];
                float m = fmaxf(v0, v1);
                for (int s = 32; s; s >>= 1) m = fmaxf(m, __shfl_xor(m, s, 64));
                float se = expf(v0 - m) + expf(v1 - m);
                for (int s = 32; s; s >>= 1) se += __shfl_xor(se, s, 64);
                float lse = m + logf(se);
                float o0 = s_x[p2][cA], o1 = s_x[p2][cB];
                float term = o0*(v0 - lse) + o1*(v1 - lse);
                for (int s = 32; s; s >>= 1) term += __shfl_xor(term, s, 64);
                if (lane == 0) s_ls[p2][h2] = -term;
            }
            __syncthreads();
            if (tid < 2) {
                int qq = s_q[tid];
                float n1 = s_cnt[qq+1], n2 = s_cnt[qq];
                s_loss[qq] = ((n1+EPSF)*s_ls[tid][0] + (n2+EPSF)*s_ls[tid][1]) / (n1+n2+EPSF);
            }
            __syncthreads();
        }
        // argmin over j in [0, L-1), first-occurrence tie rule; waves 0,1
        if (tid < 128) {
            float v = (tid < L-1) ? s_loss[tid] : INFINITY;
            int ii = tid;
            for (int s = 32; s; s >>= 1) {
                float ov = __shfl_xor(v, s, 64);
                int   oi = __shfl_xor(ii, s, 64);
                if (ov < v || (ov == v && oi < ii)) { v = ov; ii = oi; }
            }
            if ((tid & 63) == 0) { s_wv[tid>>6] = v; s_wi[tid>>6] = ii; }
        }
        __syncthreads();
        float bv0 = s_wv[0], bv1 = s_wv[1];
        int idx = (s_wv[1] < s_wv[0]) ? s_wi[1] : s_wi[0];
        if (tid == 0) acc += fminf(bv0, bv1);
        int pos = idx > 0 ? idx - 1 : 0;
        int slotF = s_nslot[pos];
        int ysI   = s_yslot[idx];
        float fcnt = s_cnt[idx] + s_cnt[idx == 0 ? L-1 : idx-1];
        // shifts (only when idx>0; reference does no shift for idx==0)
        bool doShift = (idx > 0);
        bool shL = doShift && tid >= pos+1 && tid <= L-3;   // loss / yslot
        bool shC = doShift && tid >= pos+1 && tid <= L-2;   // cnt / nslot
        float nl = 0.f, nc = 0.f; int nn = 0, ny = 0;
        if (shL) { nl = s_loss[tid+1]; ny = s_yslot[tid+1]; }
        if (shC) { nc = s_cnt[tid+1];  nn = s_nslot[tid+1]; }
        float fx = (tid < EMB) ? s_yc[(size_t)ysI*EMB + tid] : 0.f;
        __syncthreads();
        if (tid < EMB) s_nodes[slotF*EMB + tid] = fx;   // father node <- y of pair
        if (shL) { s_loss[tid] = nl; s_yslot[tid] = ny; }
        if (shC) { s_cnt[tid]  = nc; s_nslot[tid] = nn; }
        if (tid == 0) {
            s_cnt[pos] = fcnt;
            s_q[0] = (pos >= 1) ? pos - 1 : pos;
            s_q[1] = pos;
        }
        __syncthreads();
    }
    // prediction from final root node
    if (tid < KCLS) {
        int slot0 = s_nslot[0];
        float a = bkv[tid];
        for (int k = 0; k < EMB; ++k) a += s_nodes[slot0*EMB + k] * Wk[k*KCLS + tid];
        s_log[tid] = a;
    }
    __syncthreads();
    if (tid == 0) {
        int best = 0;
        for (int cc = 1; cc < KCLS; ++cc) if (s_log[cc] > s_log[best]) best = cc;
        out[b] = (float)best;
        atomicAdd(&out[BATCH], acc * (1.f/16.f));
    }
}

extern "C" void kernel_launch(void* const* d_in, const int* in_sizes, int n_in,
                              void* d_out, int out_size, void* d_ws, size_t ws_size,
                              hipStream_t stream) {
    const int*   inp = (const int*)d_in[0];
    const float* emb = (const float*)d_in[1];
    const float* W1  = (const float*)d_in[2];
    const float* b1  = (const float*)d_in[3];
    const float* W2  = (const float*)d_in[4];
    const float* b2  = (const float*)d_in[5];
    const float* W3  = (const float*)d_in[6];
    const float* b3  = (const float*)d_in[7];
    const float* W4  = (const float*)d_in[8];
    const float* b4  = (const float*)d_in[9];
    const float* Wk  = (const float*)d_in[10];
    const float* bk  = (const float*)d_in[11];
    float* out = (float*)d_out;
    float* ws  = (float*)d_ws;

    hipMemsetAsync(d_out, 0, (size_t)out_size * sizeof(float), stream);

    k_comp<<<(65920 + 255) / 256, 256, 0, stream>>>(W1, b1, W2, b2, W3, b3, W4, b4, ws);
    k_nodes<<<(BATCH*SEQ*EMB + 255) / 256, 256, 0, stream>>>(inp, emb, ws);
    k_init<<<BATCH * 8, 512, 0, stream>>>(ws);
    k_seq<<<BATCH, 512, 0, stream>>>(ws, Wk, bk, out);
}